// Round 2
// baseline (85.488 us; speedup 1.0000x reference)
//
#include <hip/hip_runtime.h>
#include <hip/hip_bf16.h>
#include <math.h>

#define SPANS 8
#define CHUNK 2048
#define BLOCK 256

__global__ __launch_bounds__(BLOCK) void span_iou_loss_kernel(
    const float* __restrict__ start_logits,
    const float* __restrict__ end_logits,
    const int* __restrict__ span_starts,
    const int* __restrict__ span_ends,
    float* __restrict__ out,
    int L, int chunks_per_row, float inv_BL) {

    const int blk = blockIdx.x;
    const int b = blk / chunks_per_row;
    const int chunk = blk % chunks_per_row;
    const int row_off = chunk * CHUNK;
    const long base = (long)b * L + row_off;

    // Span data: block-uniform addresses -> scalar loads, kept in registers.
    int s0[SPANS], e0[SPANS];
    float inv_len[SPANS];
#pragma unroll
    for (int s = 0; s < SPANS; ++s) {
        s0[s] = span_starts[b * SPANS + s];
        e0[s] = span_ends[b * SPANS + s];
        // May be inf/garbage for invalid spans (s>e); never selected below.
        inv_len[s] = 1.0f / (float)(e0[s] - s0[s] + 1);
    }

    const float4* sl4 = reinterpret_cast<const float4*>(start_logits + base);
    const float4* el4 = reinterpret_cast<const float4*>(end_logits + base);

    float acc = 0.0f;
#pragma unroll
    for (int it = 0; it < CHUNK / 4 / BLOCK; ++it) {
        const int v = it * BLOCK + threadIdx.x;   // float4 index within chunk
        const float4 xs = sl4[v];
        const float4 xe = el4[v];
        const int i0 = row_off + v * 4;
        const float xsa[4] = {xs.x, xs.y, xs.z, xs.w};
        const float xea[4] = {xe.x, xe.y, xe.z, xe.w};
#pragma unroll
        for (int j = 0; j < 4; ++j) {
            const int i = i0 + j;
            float miou = 0.0f;
            bool lblS = false, lblE = false;
#pragma unroll
            for (int s = 0; s < SPANS; ++s) {
                lblS = lblS || (s0[s] == i);
                lblE = lblE || (e0[s] == i);
                const float cand = (s0[s] <= i && i <= e0[s]) ? inv_len[s] : 0.0f;
                miou = fmaxf(miou, cand);
            }
            const float om = 1.0f + miou;
            const float negw = 0.25f * om * om;   // ALPHA*(1+miou)^GAMMA, GAMMA=2

            // start branch
            {
                const float x = xsa[j];
                const float y = lblS ? 1.0f : 0.0f;
                const float w = lblS ? 0.75f : negw;
                const float bce = fmaxf(x, 0.0f) - x * y + log1pf(__expf(-fabsf(x)));
                acc += w * bce;
            }
            // end branch
            {
                const float x = xea[j];
                const float y = lblE ? 1.0f : 0.0f;
                const float w = lblE ? 0.75f : negw;
                const float bce = fmaxf(x, 0.0f) - x * y + log1pf(__expf(-fabsf(x)));
                acc += w * bce;
            }
        }
    }

    acc *= inv_BL;   // mean over B*L (applies to both start+end parts summed)

    // wave (64-lane) reduction
#pragma unroll
    for (int off = 32; off > 0; off >>= 1) acc += __shfl_down(acc, off);

    __shared__ float wsum[BLOCK / 64];
    const int lane = threadIdx.x & 63;
    const int wid = threadIdx.x >> 6;
    if (lane == 0) wsum[wid] = acc;
    __syncthreads();
    if (threadIdx.x == 0) {
        float t = 0.0f;
#pragma unroll
        for (int w = 0; w < BLOCK / 64; ++w) t += wsum[w];
        atomicAdd(out, t);
    }
}

extern "C" void kernel_launch(void* const* d_in, const int* in_sizes, int n_in,
                              void* d_out, int out_size, void* d_ws, size_t ws_size,
                              hipStream_t stream) {
    const float* start_logits = (const float*)d_in[0];
    const float* end_logits   = (const float*)d_in[1];
    const int*   span_starts  = (const int*)d_in[2];
    const int*   span_ends    = (const int*)d_in[3];
    float* out = (float*)d_out;

    const int B = in_sizes[2] / SPANS;          // 256
    const int L = in_sizes[0] / B;              // 8192
    const int chunks_per_row = L / CHUNK;       // 4
    const float inv_BL = 1.0f / ((float)B * (float)L);

    // d_out is re-poisoned to 0xAA before every timed launch -> zero it here.
    hipMemsetAsync(d_out, 0, sizeof(float) * out_size, stream);

    dim3 grid(B * chunks_per_row);
    dim3 block(BLOCK);
    span_iou_loss_kernel<<<grid, block, 0, stream>>>(
        start_logits, end_logits, span_starts, span_ends, out, L, chunks_per_row, inv_BL);
}

// Round 3
// 82.753 us; speedup vs baseline: 1.0330x; 1.0330x over previous
//
#include <hip/hip_runtime.h>
#include <hip/hip_bf16.h>
#include <math.h>

#define SPANS 8
#define CHUNK 2048
#define BLOCK 256

__global__ __launch_bounds__(BLOCK) void span_iou_loss_kernel(
    const float* __restrict__ start_logits,
    const float* __restrict__ end_logits,
    const int* __restrict__ span_starts,
    const int* __restrict__ span_ends,
    float* __restrict__ out,
    int L, int chunks_per_row, float inv_BL) {

    const int blk = blockIdx.x;
    const int b = blk / chunks_per_row;
    const int chunk = blk % chunks_per_row;
    const int row_off = chunk * CHUNK;
    const long base = (long)b * L + row_off;

    // Span data: block-uniform addresses -> scalar loads, kept in registers.
    int s0[SPANS], e0[SPANS];
    float inv_len[SPANS];
#pragma unroll
    for (int s = 0; s < SPANS; ++s) {
        s0[s] = span_starts[b * SPANS + s];
        e0[s] = span_ends[b * SPANS + s];
        // May be inf/garbage for invalid spans (s>e); never selected below.
        inv_len[s] = 1.0f / (float)(e0[s] - s0[s] + 1);
    }

    const float4* sl4 = reinterpret_cast<const float4*>(start_logits + base);
    const float4* el4 = reinterpret_cast<const float4*>(end_logits + base);

    float acc = 0.0f;
#pragma unroll
    for (int it = 0; it < CHUNK / 4 / BLOCK; ++it) {
        const int v = it * BLOCK + threadIdx.x;   // float4 index within chunk
        const float4 xs = sl4[v];
        const float4 xe = el4[v];
        const int i0 = row_off + v * 4;
        const float xsa[4] = {xs.x, xs.y, xs.z, xs.w};
        const float xea[4] = {xe.x, xe.y, xe.z, xe.w};
#pragma unroll
        for (int j = 0; j < 4; ++j) {
            const int i = i0 + j;
            float miou = 0.0f;
            bool lblS = false, lblE = false;
#pragma unroll
            for (int s = 0; s < SPANS; ++s) {
                lblS = lblS || (s0[s] == i);
                lblE = lblE || (e0[s] == i);
                const float cand = (s0[s] <= i && i <= e0[s]) ? inv_len[s] : 0.0f;
                miou = fmaxf(miou, cand);
            }
            const float om = 1.0f + miou;
            const float negw = 0.25f * om * om;   // ALPHA*(1+miou)^GAMMA, GAMMA=2

            // fast stable softplus(-|x|) = log(1 + exp(-|x|)):
            // v_exp/v_log HW ops; abs err < 1e-7 vs log1pf path, threshold is 8e-3.
            // start branch
            {
                const float x = xsa[j];
                const float y = lblS ? 1.0f : 0.0f;
                const float w = lblS ? 0.75f : negw;
                const float sp = __logf(1.0f + __expf(-fabsf(x)));
                const float bce = fmaxf(x, 0.0f) - x * y + sp;
                acc += w * bce;
            }
            // end branch
            {
                const float x = xea[j];
                const float y = lblE ? 1.0f : 0.0f;
                const float w = lblE ? 0.75f : negw;
                const float sp = __logf(1.0f + __expf(-fabsf(x)));
                const float bce = fmaxf(x, 0.0f) - x * y + sp;
                acc += w * bce;
            }
        }
    }

    acc *= inv_BL;   // mean over B*L (applies to both start+end parts summed)

    // wave (64-lane) reduction
#pragma unroll
    for (int off = 32; off > 0; off >>= 1) acc += __shfl_down(acc, off);

    __shared__ float wsum[BLOCK / 64];
    const int lane = threadIdx.x & 63;
    const int wid = threadIdx.x >> 6;
    if (lane == 0) wsum[wid] = acc;
    __syncthreads();
    if (threadIdx.x == 0) {
        float t = 0.0f;
#pragma unroll
        for (int w = 0; w < BLOCK / 64; ++w) t += wsum[w];
        atomicAdd(out, t);
    }
}

extern "C" void kernel_launch(void* const* d_in, const int* in_sizes, int n_in,
                              void* d_out, int out_size, void* d_ws, size_t ws_size,
                              hipStream_t stream) {
    const float* start_logits = (const float*)d_in[0];
    const float* end_logits   = (const float*)d_in[1];
    const int*   span_starts  = (const int*)d_in[2];
    const int*   span_ends    = (const int*)d_in[3];
    float* out = (float*)d_out;

    const int B = in_sizes[2] / SPANS;          // 256
    const int L = in_sizes[0] / B;              // 8192
    const int chunks_per_row = L / CHUNK;       // 4
    const float inv_BL = 1.0f / ((float)B * (float)L);

    // d_out is re-poisoned to 0xAA before every timed launch -> zero it here.
    hipMemsetAsync(d_out, 0, sizeof(float) * out_size, stream);

    dim3 grid(B * chunks_per_row);
    dim3 block(BLOCK);
    span_iou_loss_kernel<<<grid, block, 0, stream>>>(
        start_logits, end_logits, span_starts, span_ends, out, L, chunks_per_row, inv_BL);
}